// Round 5
// baseline (2157.474 us; speedup 1.0000x reference)
//
#include <hip/hip_runtime.h>

// CrossNetMix fused kernel: B=16384, D=1024, L=3, E=4, R=64, fp32.
// One block = 32 rows through all 3 layers. d_out serves as the x_l buffer.
// R3: 3 blocks/CU (launch_bounds 256,3), register-prefetch staging for
// GEMM1 (As+Bs) and GEMM2 (Us), gate-dot ILP. LDS layout unchanged (51.7KB).

#define TB   32      // rows per block
#define DIM  1024    // D
#define RR   64      // R
#define NE   4       // experts
#define NL   3       // layers
#define N1   256     // E*R
#define KC1  32      // GEMM1 K-chunk
#define KC2  32      // GEMM2 K-chunk
#define NC2  128     // GEMM2 N-chunk

struct SM {
  union {
    struct {                       // GEMM1 staging
      float As[KC1][TB + 4];       // [k][row], stride 36 floats
      float Bs[KC1][N1 + 4];       // [k][col], stride 260 floats
    } g1;
    struct {                       // phase-2/3 buffers
      float vbuf[TB][N1 + 4];      // [row][col]: v after GEMM1, then w = gate*tanh(c)
      float Us[KC2][NC2 + 4];      // [k][n], stride 132 floats
    } g2;
  } u;
  float gp[TB][NE][2];             // gate partial dots
  float gate[TB][NE];              // softmaxed gates
};

__global__ __launch_bounds__(256, 3)
void crossnet_kernel(const float* __restrict__ x,
                     const float* __restrict__ Uw,    // (L,E,D,R)
                     const float* __restrict__ Vw,    // (L,E,D,R)
                     const float* __restrict__ Cw,    // (L,E,R,R)
                     const float* __restrict__ bias,  // (L,D)
                     const float* __restrict__ G,     // (E,D)
                     float* __restrict__ out)         // (B,D): x_l buffer + final out
{
  __shared__ SM sm;
  const int t  = threadIdx.x;
  const int tc = t & 31;   // 0..31 (col group)
  const int tr = t >> 5;   // 0..7  (row group)
  const int b0 = blockIdx.x * TB;
  const int sr = t >> 3;   // staging row 0..31
  const int skq = t & 7;   // staging k-quad 0..7

  for (int layer = 0; layer < NL; ++layer) {
    const float* xin = (layer == 0) ? x : out;
    __syncthreads();   // order prev-layer global writes vs this layer's reads

    // -------- preload GEMM1 chunk kc=0 into regs (latency hides under gate) --------
    float4 pa, pb[8];
    pa = *reinterpret_cast<const float4*>(xin + (size_t)(b0 + sr) * DIM + skq * 4);
    #pragma unroll
    for (int j = 0; j < 8; ++j) {
      const int p = j * 256 + t;
      const int k = p >> 6;
      const int col = (p & 63) * 4;
      const int e = col >> 6, r = col & 63;
      pb[j] = *reinterpret_cast<const float4*>(
          Vw + (((size_t)layer * NE + e) * DIM + (size_t)k) * RR + r);
    }

    // ---------------- gate pass: gp[b][e] = G[e,:] . x_l[b,:] ----------------
    {
      const int gb = t >> 3;        // 0..31 row
      const int ge = (t >> 1) & 3;  // 0..3 expert
      const int gh = t & 1;         // half
      const float4* xr = reinterpret_cast<const float4*>(xin + (size_t)(b0 + gb) * DIM) + gh * 128;
      const float4* gr = reinterpret_cast<const float4*>(G + (size_t)ge * DIM) + gh * 128;
      float4 sa = {0.f, 0.f, 0.f, 0.f};
      for (int q = 0; q < 128; ++q) {
        float4 a = xr[q], g4 = gr[q];
        sa.x = fmaf(a.x, g4.x, sa.x);
        sa.y = fmaf(a.y, g4.y, sa.y);
        sa.z = fmaf(a.z, g4.z, sa.z);
        sa.w = fmaf(a.w, g4.w, sa.w);
      }
      sm.gp[gb][ge][gh] = (sa.x + sa.y) + (sa.z + sa.w);
    }
    __syncthreads();
    if (t < TB) {                   // softmax over experts for row t
      float z[NE];
      float m = -1e30f;
      #pragma unroll
      for (int e = 0; e < NE; ++e) { z[e] = sm.gp[t][e][0] + sm.gp[t][e][1]; m = fmaxf(m, z[e]); }
      float den = 0.f;
      #pragma unroll
      for (int e = 0; e < NE; ++e) { z[e] = expf(z[e] - m); den += z[e]; }
      const float inv = 1.f / den;
      #pragma unroll
      for (int e = 0; e < NE; ++e) sm.gate[t][e] = z[e] * inv;
    }

    // ---------------- GEMM1: v_pre(32x256) = x_tile(32x1024) @ V'(1024x256) ----------------
    float acc[4][8];
    #pragma unroll
    for (int r2 = 0; r2 < 4; ++r2)
      #pragma unroll
      for (int j = 0; j < 8; ++j) acc[r2][j] = 0.f;

    for (int kc = 0; kc < DIM / KC1; ++kc) {
      __syncthreads();   // prior chunk reads done (iter 0: gate/gp writes ordered)
      // write prefetched regs -> LDS
      sm.u.g1.As[skq * 4 + 0][sr] = pa.x;
      sm.u.g1.As[skq * 4 + 1][sr] = pa.y;
      sm.u.g1.As[skq * 4 + 2][sr] = pa.z;
      sm.u.g1.As[skq * 4 + 3][sr] = pa.w;
      #pragma unroll
      for (int j = 0; j < 8; ++j) {
        const int p = j * 256 + t;
        const int k = p >> 6;
        const int col = (p & 63) * 4;
        *reinterpret_cast<float4*>(&sm.u.g1.Bs[k][col]) = pb[j];
      }
      __syncthreads();
      // issue next chunk's global loads (latency hides under compute below)
      if (kc + 1 < DIM / KC1) {
        pa = *reinterpret_cast<const float4*>(
            xin + (size_t)(b0 + sr) * DIM + (kc + 1) * KC1 + skq * 4);
        #pragma unroll
        for (int j = 0; j < 8; ++j) {
          const int p = j * 256 + t;
          const int k = p >> 6;
          const int col = (p & 63) * 4;
          const int e = col >> 6, r = col & 63;
          pb[j] = *reinterpret_cast<const float4*>(
              Vw + (((size_t)layer * NE + e) * DIM + (size_t)((kc + 1) * KC1 + k)) * RR + r);
        }
      }
      #pragma unroll 8
      for (int k = 0; k < KC1; ++k) {
        const float4 av  = *reinterpret_cast<const float4*>(&sm.u.g1.As[k][tr * 4]);
        const float4 bv0 = *reinterpret_cast<const float4*>(&sm.u.g1.Bs[k][tc * 4]);
        const float4 bv1 = *reinterpret_cast<const float4*>(&sm.u.g1.Bs[k][128 + tc * 4]);
        const float aa[4] = {av.x, av.y, av.z, av.w};
        const float bb[8] = {bv0.x, bv0.y, bv0.z, bv0.w, bv1.x, bv1.y, bv1.z, bv1.w};
        #pragma unroll
        for (int r2 = 0; r2 < 4; ++r2)
          #pragma unroll
          for (int j = 0; j < 8; ++j)
            acc[r2][j] = fmaf(aa[r2], bb[j], acc[r2][j]);
      }
    }
    __syncthreads();   // all Bs/As reads done -> safe to overwrite union with vbuf

    // v = tanh(v_pre) -> vbuf
    #pragma unroll
    for (int r2 = 0; r2 < 4; ++r2) {
      const int b = tr * 4 + r2;
      #pragma unroll
      for (int g = 0; g < 2; ++g) {
        float4 w4;
        w4.x = tanhf(acc[r2][g * 4 + 0]);
        w4.y = tanhf(acc[r2][g * 4 + 1]);
        w4.z = tanhf(acc[r2][g * 4 + 2]);
        w4.w = tanhf(acc[r2][g * 4 + 3]);
        *reinterpret_cast<float4*>(&sm.u.g2.vbuf[b][g * 128 + tc * 4]) = w4;
      }
    }
    __syncthreads();

    // preload first GEMM2 Us chunk (s=0: nc=0, kc2=0 -> e=0, rb=0); hides under C-step
    float4 pu[4];
    #pragma unroll
    for (int j = 0; j < 4; ++j) {
      const int p = j * 256 + t;
      const int n = p >> 3;
      const int kq = p & 7;
      pu[j] = *reinterpret_cast<const float4*>(
          Uw + ((size_t)layer * NE * DIM + (size_t)n) * RR + kq * 4);
    }

    // ---------------- C-step: c[b][e,r] = sum_s C[l,e,r,s] * v[b][e,s] ----------------
    float cacc[4][8];
    #pragma unroll
    for (int r2 = 0; r2 < 4; ++r2)
      #pragma unroll
      for (int j = 0; j < 8; ++j) cacc[r2][j] = 0.f;

    #pragma unroll
    for (int g = 0; g < 2; ++g) {
      const int colbase = g * 128 + tc * 4;
      const int e = colbase >> 6;
      const int rbase = colbase & 63;
      const float* Crow = Cw + ((size_t)layer * NE + e) * RR * RR;
      for (int s4 = 0; s4 < 16; ++s4) {
        float4 v4[4];
        #pragma unroll
        for (int r2 = 0; r2 < 4; ++r2)
          v4[r2] = *reinterpret_cast<const float4*>(&sm.u.g2.vbuf[tr * 4 + r2][e * 64 + s4 * 4]);
        #pragma unroll
        for (int j = 0; j < 4; ++j) {
          const float4 c4 = *reinterpret_cast<const float4*>(Crow + (size_t)(rbase + j) * RR + s4 * 4);
          #pragma unroll
          for (int r2 = 0; r2 < 4; ++r2)
            cacc[r2][g * 4 + j] += c4.x * v4[r2].x + c4.y * v4[r2].y +
                                   c4.z * v4[r2].z + c4.w * v4[r2].w;
        }
      }
    }
    __syncthreads();   // all v reads done -> safe to overwrite vbuf with w

    // w = gate * tanh(c) -> vbuf
    #pragma unroll
    for (int g = 0; g < 2; ++g) {
      const int colbase = g * 128 + tc * 4;
      const int e = colbase >> 6;
      #pragma unroll
      for (int r2 = 0; r2 < 4; ++r2) {
        const int b = tr * 4 + r2;
        const float gt = sm.gate[b][e];
        float4 w4;
        w4.x = gt * tanhf(cacc[r2][g * 4 + 0]);
        w4.y = gt * tanhf(cacc[r2][g * 4 + 1]);
        w4.z = gt * tanhf(cacc[r2][g * 4 + 2]);
        w4.w = gt * tanhf(cacc[r2][g * 4 + 3]);
        *reinterpret_cast<float4*>(&sm.u.g2.vbuf[b][colbase]) = w4;
      }
    }

    // ---------------- GEMM2 + combine: ubar(32x1024) = w(32x256) @ U'(256x1024) ----------------
    for (int nc = 0; nc < DIM / NC2; ++nc) {
      float acc2[4][4];
      #pragma unroll
      for (int r2 = 0; r2 < 4; ++r2)
        #pragma unroll
        for (int j = 0; j < 4; ++j) acc2[r2][j] = 0.f;

      for (int kc2 = 0; kc2 < N1 / KC2; ++kc2) {
        __syncthreads();   // guards w writes (iter 0) / prior Us reads
        #pragma unroll
        for (int j = 0; j < 4; ++j) {   // write prefetched Us regs -> LDS
          const int p = j * 256 + t;
          const int n = p >> 3;         // 0..127
          const int kq = p & 7;
          sm.u.g2.Us[kq * 4 + 0][n] = pu[j].x;
          sm.u.g2.Us[kq * 4 + 1][n] = pu[j].y;
          sm.u.g2.Us[kq * 4 + 2][n] = pu[j].z;
          sm.u.g2.Us[kq * 4 + 3][n] = pu[j].w;
        }
        __syncthreads();
        {  // issue next staging's loads (hides under k4 compute)
          const int s = nc * (N1 / KC2) + kc2;
          if (s + 1 < (DIM / NC2) * (N1 / KC2)) {
            const int sn = s + 1;
            const int ncn = sn >> 3, kc2n = sn & 7;
            const int en = kc2n >> 1, rbn = (kc2n & 1) * 32;
            #pragma unroll
            for (int j = 0; j < 4; ++j) {
              const int p = j * 256 + t;
              const int n = p >> 3;
              const int kq = p & 7;
              pu[j] = *reinterpret_cast<const float4*>(
                  Uw + (((size_t)layer * NE + en) * DIM + (size_t)(ncn * NC2 + n)) * RR + rbn + kq * 4);
            }
          }
        }
        #pragma unroll
        for (int k4 = 0; k4 < KC2 / 4; ++k4) {
          float wv[4][4];
          #pragma unroll
          for (int r2 = 0; r2 < 4; ++r2) {
            const float4 wq = *reinterpret_cast<const float4*>(
                &sm.u.g2.vbuf[tr * 4 + r2][kc2 * KC2 + k4 * 4]);
            wv[r2][0] = wq.x; wv[r2][1] = wq.y; wv[r2][2] = wq.z; wv[r2][3] = wq.w;
          }
          #pragma unroll
          for (int kk = 0; kk < 4; ++kk) {
            const float4 u4 = *reinterpret_cast<const float4*>(&sm.u.g2.Us[k4 * 4 + kk][tc * 4]);
            const float uu[4] = {u4.x, u4.y, u4.z, u4.w};
            #pragma unroll
            for (int r2 = 0; r2 < 4; ++r2)
              #pragma unroll
              for (int j = 0; j < 4; ++j)
                acc2[r2][j] = fmaf(wv[r2][kk], uu[j], acc2[r2][j]);
          }
        }
      }
      // combine: x_l_new = x0 * (ubar + bias) + x_l   (softmax gates sum to 1)
      const int d0 = nc * NC2 + tc * 4;
      const float4 bv = *reinterpret_cast<const float4*>(bias + (size_t)layer * DIM + d0);
      #pragma unroll
      for (int r2 = 0; r2 < 4; ++r2) {
        const size_t off = (size_t)(b0 + tr * 4 + r2) * DIM + d0;
        const float4 x0v = *reinterpret_cast<const float4*>(x + off);
        const float4 xlv = *reinterpret_cast<const float4*>(xin + off);
        float4 o;
        o.x = x0v.x * (acc2[r2][0] + bv.x) + xlv.x;
        o.y = x0v.y * (acc2[r2][1] + bv.y) + xlv.y;
        o.z = x0v.z * (acc2[r2][2] + bv.z) + xlv.z;
        o.w = x0v.w * (acc2[r2][3] + bv.w) + xlv.w;
        *reinterpret_cast<float4*>(out + off) = o;
      }
    }
  }
}

extern "C" void kernel_launch(void* const* d_in, const int* in_sizes, int n_in,
                              void* d_out, int out_size, void* d_ws, size_t ws_size,
                              hipStream_t stream) {
  const float* x    = (const float*)d_in[0];
  const float* Uw   = (const float*)d_in[1];
  const float* Vw   = (const float*)d_in[2];
  const float* Cw   = (const float*)d_in[3];
  const float* bias = (const float*)d_in[4];
  const float* G    = (const float*)d_in[5];
  float* out = (float*)d_out;

  const int B = in_sizes[0] / DIM;   // 16384
  dim3 grid(B / TB), block(256);
  hipLaunchKernelGGL(crossnet_kernel, grid, block, 0, stream,
                     x, Uw, Vw, Cw, bias, G, out);
}

// Round 7
// 960.845 us; speedup vs baseline: 2.2454x; 2.2454x over previous
//
#include <hip/hip_runtime.h>

// CrossNetMix fused, MFMA path: B=16384, D=1024, L=3, E=4, R=64.
// GEMM1 (x@V' 1024x256) and GEMM2 (w@U' 256x1024) run on matrix cores via
// bf16 hi/lo split (3 MFMAs per product: AhBh + AhBl + AlBh, ~2^-18 rel err).
// Kernel 1 pre-converts V,U into fragment-linear bf16 hi/lo in d_ws (6.3MB).
// Kernel 2: one block = 32 rows through all 3 layers; B-frags stream from L2.
// mfma_f32_16x16x32_bf16: A[m=l&15][k], B[k][n=l&15], D[m=(l>>4)*4+reg][n=l&15].
// k-permutation within a K-step cancels between A and B frags (both use
// k = ks*32 + (l>>4)*8 + i), so only the m/n/D mappings must be exact.

typedef __bf16 bf16x8 __attribute__((ext_vector_type(8)));
typedef float f32x4 __attribute__((ext_vector_type(4)));
typedef unsigned short u16;
typedef unsigned int u32;

#define TB   32
#define DIM  1024
#define RR   64
#define NE   4
#define NL   3
#define N1   256

#define VF_PER_LAYER (16*32*2*64*8)   // 524288 u16 per layer (ct,ks,h,lane,i)
#define UF_PER_LAYER (64*8*2*64*8)    // 524288 u16 per layer
#define VF_TOTAL (NL*VF_PER_LAYER)
#define UF_TOTAL (NL*UF_PER_LAYER)

#define MFMA16(a,b,c) __builtin_amdgcn_mfma_f32_16x16x32_bf16(a,b,c,0,0,0)

__device__ __forceinline__ u16 f2bf(float f) {
  u32 u = __float_as_uint(f);
  u32 r = (u + 0x7FFFu + ((u >> 16) & 1u)) >> 16;   // RNE
  return (u16)r;
}
__device__ __forceinline__ float bf2f(u16 b) {
  return __uint_as_float(((u32)b) << 16);
}
__device__ __forceinline__ bf16x8 ld_frag_g(const u16* p) {
  return __builtin_bit_cast(bf16x8, *reinterpret_cast<const uint4*>(p));
}

// ---------- kernel 1: convert V,U fp32 -> fragment-linear bf16 hi/lo ----------
__global__ __launch_bounds__(256)
void convert_frags(const float* __restrict__ Vw, const float* __restrict__ Uw,
                   u16* __restrict__ Vf, u16* __restrict__ Uf) {
  const int id = blockIdx.x * 256 + threadIdx.x;   // 0 .. 196607
  float f[8];
  if (id < NL * 16 * 32 * 64) {            // V path: (l, ct, ks, lane)
    const int lane = id & 63;
    const int ks   = (id >> 6) & 31;
    const int ct   = (id >> 11) & 15;
    const int l    = id >> 15;
    const int col  = ct * 16 + (lane & 15);      // e*64 + r
    const int e = col >> 6, r = col & 63;
    const int kbase = ks * 32 + (lane >> 4) * 8;
    const float* src = Vw + ((size_t)(l * NE + e) * DIM + kbase) * RR + r;
    #pragma unroll
    for (int i = 0; i < 8; ++i) f[i] = src[(size_t)i * RR];
    u16* dst = Vf + (size_t)l * VF_PER_LAYER + ((((size_t)ct * 32 + ks) * 2) * 64 + lane) * 8;
    uint4 hi, lo;
    u16 h[8], lw[8];
    #pragma unroll
    for (int i = 0; i < 8; ++i) { h[i] = f2bf(f[i]); lw[i] = f2bf(f[i] - bf2f(h[i])); }
    hi.x = h[0] | (u32)h[1] << 16;  hi.y = h[2] | (u32)h[3] << 16;
    hi.z = h[4] | (u32)h[5] << 16;  hi.w = h[6] | (u32)h[7] << 16;
    lo.x = lw[0] | (u32)lw[1] << 16; lo.y = lw[2] | (u32)lw[3] << 16;
    lo.z = lw[4] | (u32)lw[5] << 16; lo.w = lw[6] | (u32)lw[7] << 16;
    *reinterpret_cast<uint4*>(dst) = hi;
    *reinterpret_cast<uint4*>(dst + 512) = lo;   // h=1 block
  } else {                                  // U path: (l, ct, ks, lane)
    const int u = id - NL * 16 * 32 * 64;
    const int lane = u & 63;
    const int ks   = (u >> 6) & 7;
    const int ct   = (u >> 9) & 63;
    const int l    = u >> 15;
    const int d    = ct * 16 + (lane & 15);
    const int kk   = ks * 32 + (lane >> 4) * 8;  // e*64 + r
    const int e = kk >> 6, rb = kk & 63;
    const float* src = Uw + ((size_t)(l * NE + e) * DIM + d) * RR + rb;
    #pragma unroll
    for (int i = 0; i < 8; ++i) f[i] = src[i];
    u16* dst = Uf + (size_t)l * UF_PER_LAYER + ((((size_t)ct * 8 + ks) * 2) * 64 + lane) * 8;
    uint4 hi, lo;
    u16 h[8], lw[8];
    #pragma unroll
    for (int i = 0; i < 8; ++i) { h[i] = f2bf(f[i]); lw[i] = f2bf(f[i] - bf2f(h[i])); }
    hi.x = h[0] | (u32)h[1] << 16;  hi.y = h[2] | (u32)h[3] << 16;
    hi.z = h[4] | (u32)h[5] << 16;  hi.w = h[6] | (u32)h[7] << 16;
    lo.x = lw[0] | (u32)lw[1] << 16; lo.y = lw[2] | (u32)lw[3] << 16;
    lo.z = lw[4] | (u32)lw[5] << 16; lo.w = lw[6] | (u32)lw[7] << 16;
    *reinterpret_cast<uint4*>(dst) = hi;
    *reinterpret_cast<uint4*>(dst + 512) = lo;
  }
}

// ---------- kernel 2: fused 3-layer CrossNetMix ----------
struct SM2 {
  union {
    u16 Ax[2][8][2][64][8];    // GEMM1 A-frags for one K-chunk of 256 (32KB)
    u16 Wf[2][8][2][64][8];    // GEMM2 A-frags (w), K=256 (32KB)
  } u;
  float vbuf[TB][N1 + 4];      // 33.3KB, v after GEMM1 (row-major, stride 260)
  float gp[TB][NE][2];
  float gate[TB][NE];
};

__global__ __launch_bounds__(256, 2)
void crossnet_mfma(const float* __restrict__ x,
                   const float* __restrict__ Cw,    // (L,E,R,R)
                   const float* __restrict__ bias,  // (L,D)
                   const float* __restrict__ G,     // (E,D)
                   const u16* __restrict__ Vf, const u16* __restrict__ Uf,
                   float* __restrict__ out) {
  __shared__ SM2 sm;
  const int t    = threadIdx.x;
  const int lane = t & 63;
  const int wv   = t >> 6;          // wave 0..3
  const int l15  = lane & 15;
  const int lg   = lane >> 4;       // 0..3
  const int b0   = blockIdx.x * TB;
  const int tc   = t & 31, tr = t >> 5;   // C-step mapping (legacy, verified)

  for (int layer = 0; layer < NL; ++layer) {
    const float* xin = (layer == 0) ? x : out;
    const u16* Vfl = Vf + (size_t)layer * VF_PER_LAYER;
    const u16* Ufl = Uf + (size_t)layer * UF_PER_LAYER;
    __syncthreads();   // prev layer's global writes visible within block

    // ---- gate pass: gp[b][e] = G[e,:] . x_l[b,:] ----
    {
      const int gb = t >> 3, ge = (t >> 1) & 3, gh = t & 1;
      const float4* xr = reinterpret_cast<const float4*>(xin + (size_t)(b0 + gb) * DIM) + gh * 128;
      const float4* gr = reinterpret_cast<const float4*>(G + (size_t)ge * DIM) + gh * 128;
      float4 sa = {0.f, 0.f, 0.f, 0.f};
      for (int q = 0; q < 128; ++q) {
        float4 a = xr[q], g4 = gr[q];
        sa.x = fmaf(a.x, g4.x, sa.x); sa.y = fmaf(a.y, g4.y, sa.y);
        sa.z = fmaf(a.z, g4.z, sa.z); sa.w = fmaf(a.w, g4.w, sa.w);
      }
      sm.gp[gb][ge][gh] = (sa.x + sa.y) + (sa.z + sa.w);
    }
    __syncthreads();
    if (t < TB) {
      float z[NE]; float m = -1e30f;
      #pragma unroll
      for (int e = 0; e < NE; ++e) { z[e] = sm.gp[t][e][0] + sm.gp[t][e][1]; m = fmaxf(m, z[e]); }
      float den = 0.f;
      #pragma unroll
      for (int e = 0; e < NE; ++e) { z[e] = expf(z[e] - m); den += z[e]; }
      const float inv = 1.f / den;
      #pragma unroll
      for (int e = 0; e < NE; ++e) sm.gate[t][e] = z[e] * inv;
    }

    // ---- GEMM1: v_pre(32x256) = x(32x1024) @ V'(1024x256), bf16x3 MFMA ----
    f32x4 acc[2][4];
    #pragma unroll
    for (int rt = 0; rt < 2; ++rt)
      #pragma unroll
      for (int c = 0; c < 4; ++c) acc[rt][c] = (f32x4){0.f, 0.f, 0.f, 0.f};

    for (int ch = 0; ch < 4; ++ch) {        // K-chunks of 256
      __syncthreads();                       // prior chunk's Ax reads done
      #pragma unroll
      for (int q = 0; q < 8; ++q) {          // stage A chunk -> frag layout
        const int idx = q * 256 + t;
        const int r = idx >> 6, k4 = idx & 63;
        const float4 v = *reinterpret_cast<const float4*>(
            xin + (size_t)(b0 + r) * DIM + ch * 256 + k4 * 4);
        const int kk = k4 * 4;
        const int ksl = kk >> 5, ii = kk & 7, rt = r >> 4;
        const int lnf = (((kk >> 3) & 3) << 4) | (r & 15);
        u16 h0 = f2bf(v.x), h1 = f2bf(v.y), h2 = f2bf(v.z), h3 = f2bf(v.w);
        u16 e0 = f2bf(v.x - bf2f(h0)), e1 = f2bf(v.y - bf2f(h1));
        u16 e2 = f2bf(v.z - bf2f(h2)), e3 = f2bf(v.w - bf2f(h3));
        uint2 hw, lw;
        hw.x = h0 | (u32)h1 << 16; hw.y = h2 | (u32)h3 << 16;
        lw.x = e0 | (u32)e1 << 16; lw.y = e2 | (u32)e3 << 16;
        *reinterpret_cast<uint2*>(&sm.u.Ax[rt][ksl][0][lnf][ii]) = hw;
        *reinterpret_cast<uint2*>(&sm.u.Ax[rt][ksl][1][lnf][ii]) = lw;
      }
      __syncthreads();
      for (int ks = 0; ks < 8; ++ks) {
        const bf16x8 ah0 = __builtin_bit_cast(bf16x8, *(const uint4*)&sm.u.Ax[0][ks][0][lane][0]);
        const bf16x8 al0 = __builtin_bit_cast(bf16x8, *(const uint4*)&sm.u.Ax[0][ks][1][lane][0]);
        const bf16x8 ah1 = __builtin_bit_cast(bf16x8, *(const uint4*)&sm.u.Ax[1][ks][0][lane][0]);
        const bf16x8 al1 = __builtin_bit_cast(bf16x8, *(const uint4*)&sm.u.Ax[1][ks][1][lane][0]);
        const int kg = ch * 8 + ks;
        #pragma unroll
        for (int c = 0; c < 4; ++c) {
          const int ct = wv * 4 + c;
          const u16* p = Vfl + ((((size_t)ct * 32 + kg) * 2) * 64 + lane) * 8;
          const bf16x8 bh = ld_frag_g(p);
          const bf16x8 bl = ld_frag_g(p + 512);
          acc[0][c] = MFMA16(ah0, bh, acc[0][c]);
          acc[0][c] = MFMA16(ah0, bl, acc[0][c]);
          acc[0][c] = MFMA16(al0, bh, acc[0][c]);
          acc[1][c] = MFMA16(ah1, bh, acc[1][c]);
          acc[1][c] = MFMA16(ah1, bl, acc[1][c]);
          acc[1][c] = MFMA16(al1, bh, acc[1][c]);
        }
      }
    }
    // epilogue: v = tanh(v_pre) -> vbuf[row][col]
    #pragma unroll
    for (int rt = 0; rt < 2; ++rt)
      #pragma unroll
      for (int c = 0; c < 4; ++c)
        #pragma unroll
        for (int reg = 0; reg < 4; ++reg) {
          const int row = rt * 16 + lg * 4 + reg;
          const int col = (wv * 4 + c) * 16 + l15;
          sm.vbuf[row][col] = tanhf(acc[rt][c][reg]);
        }
    __syncthreads();   // vbuf ready; all Ax reads done (Wf union safe below)

    // ---- C-step: cacc[r2][g*4+j] = C[l,e] @ v (fp32 VALU, legacy mapping) ----
    float cacc[4][8];
    #pragma unroll
    for (int r2 = 0; r2 < 4; ++r2)
      #pragma unroll
      for (int j = 0; j < 8; ++j) cacc[r2][j] = 0.f;
    #pragma unroll
    for (int g = 0; g < 2; ++g) {
      const int colbase = g * 128 + tc * 4;
      const int e = colbase >> 6, rbase = colbase & 63;
      const float* Crow = Cw + ((size_t)layer * NE + e) * RR * RR;
      for (int s4 = 0; s4 < 16; ++s4) {
        float4 v4[4];
        #pragma unroll
        for (int r2 = 0; r2 < 4; ++r2)
          v4[r2] = *reinterpret_cast<const float4*>(&sm.vbuf[tr * 4 + r2][e * 64 + s4 * 4]);
        #pragma unroll
        for (int j = 0; j < 4; ++j) {
          const float4 c4 = *reinterpret_cast<const float4*>(Crow + (size_t)(rbase + j) * RR + s4 * 4);
          #pragma unroll
          for (int r2 = 0; r2 < 4; ++r2)
            cacc[r2][g * 4 + j] += c4.x * v4[r2].x + c4.y * v4[r2].y +
                                   c4.z * v4[r2].z + c4.w * v4[r2].w;
        }
      }
    }

    // ---- w = gate*tanh(c): write directly as GEMM2 A-frags (hi/lo) ----
    #pragma unroll
    for (int g = 0; g < 2; ++g)
      #pragma unroll
      for (int r2 = 0; r2 < 4; ++r2) {
        const int row = tr * 4 + r2;
        const int rt = row >> 4;
        const int colb = g * 128 + tc * 4;             // k-dim of GEMM2
        const int ksl = colb >> 5, ii = colb & 7;
        const int lnf = (((colb >> 3) & 3) << 4) | (row & 15);
        const float gt = sm.gate[row][colb >> 6];
        u16 h[4], e4[4];
        #pragma unroll
        for (int j = 0; j < 4; ++j) {
          const float wval = gt * tanhf(cacc[r2][g * 4 + j]);
          h[j] = f2bf(wval); e4[j] = f2bf(wval - bf2f(h[j]));
        }
        uint2 hw, lw;
        hw.x = h[0] | (u32)h[1] << 16; hw.y = h[2] | (u32)h[3] << 16;
        lw.x = e4[0] | (u32)e4[1] << 16; lw.y = e4[2] | (u32)e4[3] << 16;
        *reinterpret_cast<uint2*>(&sm.u.Wf[rt][ksl][0][lnf][ii]) = hw;
        *reinterpret_cast<uint2*>(&sm.u.Wf[rt][ksl][1][lnf][ii]) = lw;
      }
    __syncthreads();

    // ---- GEMM2 + combine: ubar(32x1024) = w(32x256) @ U'(256x1024) ----
    for (int nc = 0; nc < 4; ++nc) {
      f32x4 a2[2][4];
      #pragma unroll
      for (int rt = 0; rt < 2; ++rt)
        #pragma unroll
        for (int c = 0; c < 4; ++c) a2[rt][c] = (f32x4){0.f, 0.f, 0.f, 0.f};
      for (int ks = 0; ks < 8; ++ks) {
        const bf16x8 ah0 = __builtin_bit_cast(bf16x8, *(const uint4*)&sm.u.Wf[0][ks][0][lane][0]);
        const bf16x8 al0 = __builtin_bit_cast(bf16x8, *(const uint4*)&sm.u.Wf[0][ks][1][lane][0]);
        const bf16x8 ah1 = __builtin_bit_cast(bf16x8, *(const uint4*)&sm.u.Wf[1][ks][0][lane][0]);
        const bf16x8 al1 = __builtin_bit_cast(bf16x8, *(const uint4*)&sm.u.Wf[1][ks][1][lane][0]);
        #pragma unroll
        for (int c = 0; c < 4; ++c) {
          const int ct = nc * 16 + wv * 4 + c;
          const u16* p = Ufl + ((((size_t)ct * 8 + ks) * 2) * 64 + lane) * 8;
          const bf16x8 bh = ld_frag_g(p);
          const bf16x8 bl = ld_frag_g(p + 512);
          a2[0][c] = MFMA16(ah0, bh, a2[0][c]);
          a2[0][c] = MFMA16(ah0, bl, a2[0][c]);
          a2[0][c] = MFMA16(al0, bh, a2[0][c]);
          a2[1][c] = MFMA16(ah1, bh, a2[1][c]);
          a2[1][c] = MFMA16(ah1, bl, a2[1][c]);
          a2[1][c] = MFMA16(al1, bh, a2[1][c]);
        }
      }
      // combine: out = x0*(ubar + bias) + x_l  (gates sum to 1)
      #pragma unroll
      for (int rt = 0; rt < 2; ++rt)
        #pragma unroll
        for (int c = 0; c < 4; ++c) {
          const int col = (nc * 16 + wv * 4 + c) * 16 + l15;
          const float bv = bias[(size_t)layer * DIM + col];
          #pragma unroll
          for (int reg = 0; reg < 4; ++reg) {
            const int row = rt * 16 + lg * 4 + reg;
            const size_t off = (size_t)(b0 + row) * DIM + col;
            out[off] = x[off] * (a2[rt][c][reg] + bv) + xin[off];
          }
        }
    }
  }
}

extern "C" void kernel_launch(void* const* d_in, const int* in_sizes, int n_in,
                              void* d_out, int out_size, void* d_ws, size_t ws_size,
                              hipStream_t stream) {
  const float* x    = (const float*)d_in[0];
  const float* Uw   = (const float*)d_in[1];
  const float* Vw   = (const float*)d_in[2];
  const float* Cw   = (const float*)d_in[3];
  const float* bias = (const float*)d_in[4];
  const float* G    = (const float*)d_in[5];
  float* out = (float*)d_out;
  u16* Vf = (u16*)d_ws;
  u16* Uf = Vf + VF_TOTAL;

  hipLaunchKernelGGL(convert_frags, dim3((NL * 16 * 32 * 64 + NL * 64 * 8 * 64) / 256),
                     dim3(256), 0, stream, Vw, Uw, Vf, Uf);

  const int B = in_sizes[0] / DIM;   // 16384
  hipLaunchKernelGGL(crossnet_mfma, dim3(B / TB), dim3(256), 0, stream,
                     x, Cw, bias, G, Vf, Uf, out);
}